// Round 9
// baseline (162.997 us; speedup 1.0000x reference)
//
#include <hip/hip_runtime.h>
#include <cstdint>
#include <cstddef>

// RNNT joiner: logits[b,t,u,v] = sum_j tanh(E[b,t,j]+P[b,u,j]) * out_w[v,j] + out_b[v]
// B=4 T=256 U=64 D=512 J=640 V=1024.  M = 65536 rows (b,t,u), N=1024, K=640.
//
// ws layout (Z-path):
//   E  : bf16 [1024][640]                  @ 0          (1,310,720 B)
//   P  : bf16 [ 256][640]                  @ 1,310,720  (  327,680 B)
//   Wb : bf16 [nt=4][kt=20][half=2][4096]  @ 1,638,400  (1,310,720 B)  pre-swz 128x32 tiles
//   Z  : bf16 [mt=512][kt=20][4096]        @ 2,949,120  (83,886,080 B) pre-swz 128x32 tiles
// total 86,835,200 B.  ws_size smaller -> fused fallback (R5 structure, [8][10] 128x64 Wb).

typedef __attribute__((ext_vector_type(8))) __bf16 bf16x8;
typedef __attribute__((ext_vector_type(4))) float f32x4;

// swizzle for [R][64] bf16 tiles (row stride 128B) - fallback/proj path.
__device__ __forceinline__ int swz64(int row, int kElem) {
  return (row << 6) + (kElem ^ ((row & 7) << 3));
}
// swizzle for [128][32] bf16 tiles (row stride 64B): 16B-chunk cc ^= (row&3).
// lanes 0-15 (16 rows, same chunk) -> 4 chunk values x 2 row-parities = 2-way max (free).
__device__ __forceinline__ int swz32(int row, int kElem) {
  return (row << 5) + ((kElem & 7) | (((kElem >> 3) ^ (row & 3)) << 3));
}

__device__ __forceinline__ float fast_tanh(float x) {
  float e = __builtin_amdgcn_exp2f(x * 2.88539008177793f);  // e^(2x)
  return 1.0f - 2.0f * __builtin_amdgcn_rcpf(e + 1.0f);
}

__device__ __forceinline__ void gload_lds16(const void* g, void* l) {
  __builtin_amdgcn_global_load_lds(
      (const __attribute__((address_space(1))) void*)g,
      (__attribute__((address_space(3))) void*)l, 16, 0, 0);
}

// ---------------------------------------------------------------------------
// proj tile: C[mt*128..][nt*128..] = A[128][512] . W[128][512]^T + bias  (bf16 out)
// ---------------------------------------------------------------------------
__device__ void proj_tile(const float* __restrict__ A, const float* __restrict__ W,
                          const float* __restrict__ bias, __bf16* __restrict__ C,
                          int mt, int nt, __bf16* As, __bf16* Bs)
{
  const int tid  = threadIdx.x;
  const int r = tid & 127, half = tid >> 7;
  const int lane = tid & 63, wv = tid >> 6;
  const int wm = wv >> 1, wn = wv & 1;

  const float* arow = A + (size_t)(mt * 128 + r) * 512 + half * 32;
  const float* wrow = W + (size_t)(nt * 128 + r) * 512 + half * 32;

  f32x4 acc[4][4] = {};

  for (int k0 = 0; k0 < 512; k0 += 64) {
#pragma unroll
    for (int s = 0; s < 4; ++s) {
      f32x4 a0 = *(const f32x4*)(arow + k0 + s * 8);
      f32x4 a1 = *(const f32x4*)(arow + k0 + s * 8 + 4);
      f32x4 w0 = *(const f32x4*)(wrow + k0 + s * 8);
      f32x4 w1 = *(const f32x4*)(wrow + k0 + s * 8 + 4);
      bf16x8 za, zw;
#pragma unroll
      for (int j = 0; j < 4; ++j) {
        za[j] = (__bf16)a0[j]; za[4 + j] = (__bf16)a1[j];
        zw[j] = (__bf16)w0[j]; zw[4 + j] = (__bf16)w1[j];
      }
      const int kk = half * 32 + s * 8;
      *(bf16x8*)&As[swz64(r, kk)] = za;
      *(bf16x8*)&Bs[swz64(r, kk)] = zw;
    }
    __syncthreads();
#pragma unroll
    for (int kk = 0; kk < 2; ++kk) {
      bf16x8 af[4], bfr[4];
#pragma unroll
      for (int i = 0; i < 4; ++i) {
        af[i]  = *(const bf16x8*)&As[swz64(wm * 64 + i * 16 + (lane & 15), kk * 32 + (lane >> 4) * 8)];
        bfr[i] = *(const bf16x8*)&Bs[swz64(wn * 64 + i * 16 + (lane & 15), kk * 32 + (lane >> 4) * 8)];
      }
#pragma unroll
      for (int mi = 0; mi < 4; ++mi)
#pragma unroll
        for (int ni = 0; ni < 4; ++ni)
          acc[mi][ni] = __builtin_amdgcn_mfma_f32_16x16x32_bf16(af[mi], bfr[ni], acc[mi][ni], 0, 0, 0);
    }
    __syncthreads();
  }

  const int rowbase = mt * 128 + wm * 64;
  const int colbase = nt * 128 + wn * 64;
#pragma unroll
  for (int ni = 0; ni < 4; ++ni) {
    const int col = colbase + ni * 16 + (lane & 15);
    const float bb = bias[col];
#pragma unroll
    for (int mi = 0; mi < 4; ++mi) {
      const int row = rowbase + mi * 16 + (lane >> 4) * 4;
#pragma unroll
      for (int rg = 0; rg < 4; ++rg)
        C[(size_t)(row + rg) * 640 + col] = (__bf16)(acc[mi][ni][rg] + bb);
    }
  }
}

// ---------------------------------------------------------------------------
// prep: blocks 0..39 enc-proj, 40..49 pred-proj, 50..369 out_w conversion.
// zpath=1: Wb [nt(4)][kt(20)][half(2)][128x32 swz32].
// zpath=0: Wb [nb(8)][kt(10)][128x64 swz64]  (fallback layout).
// ---------------------------------------------------------------------------
__global__ __launch_bounds__(256) void prep_kernel(
    const float* __restrict__ enc,  const float* __restrict__ enc_w,  const float* __restrict__ enc_b,
    const float* __restrict__ pred, const float* __restrict__ pred_w, const float* __restrict__ pred_b,
    const float* __restrict__ out_w,
    __bf16* __restrict__ E, __bf16* __restrict__ P, __bf16* __restrict__ Wb, int zpath)
{
  __shared__ __align__(16) __bf16 As[128 * 64];
  __shared__ __align__(16) __bf16 Bs[128 * 64];
  const int bid = blockIdx.x;
  if (bid < 40) {
    proj_tile(enc, enc_w, enc_b, E, bid / 5, bid % 5, As, Bs);
  } else if (bid < 50) {
    proj_tile(pred, pred_w, pred_b, P, (bid - 40) / 5, (bid - 40) % 5, As, Bs);
  } else {
    const int gid = (bid - 50) * 256 + threadIdx.x;  // 81920 total (1024*80)
    const int v  = gid / 80;
    const int j8 = gid % 80;
    f32x4 w0 = *(const f32x4*)(out_w + (size_t)v * 640 + j8 * 8);
    f32x4 w1 = *(const f32x4*)(out_w + (size_t)v * 640 + j8 * 8 + 4);
    bf16x8 z;
#pragma unroll
    for (int j = 0; j < 4; ++j) { z[j] = (__bf16)w0[j]; z[4 + j] = (__bf16)w1[j]; }
    if (zpath) {
      const int nt = v >> 8;
      const int half = (v >> 7) & 1;
      const int rr = v & 127;
      const int kt = j8 >> 2;                 // 8-elem group j8 -> kt (4 groups per kt)
      const int kk = (j8 & 3) * 8;            // k within kt
      *(bf16x8*)(Wb + (((size_t)(nt * 20 + kt) * 2 + half) << 12) + swz32(rr, kk)) = z;
    } else {
      const int nb = v >> 7, rr = v & 127;
      const int kb = j8 >> 3, kk = (j8 & 7) * 8;
      *(bf16x8*)(Wb + ((size_t)(nb * 10 + kb) << 13) + swz64(rr, kk)) = z;
    }
  }
}

// ---------------------------------------------------------------------------
// zprod: Z[mt][kt][4096] = tanh(E+P) for M-tile mt (128 rows), K-tile kt (32),
// written pre-swizzled (swz32) with LINEAR stores; source k inverted
// (XOR swizzle is an involution).  grid = 512*20 = 10240, 256 thr.
// ---------------------------------------------------------------------------
__global__ __launch_bounds__(256) void zprod_kernel(
    const __bf16* __restrict__ E, const __bf16* __restrict__ P,
    __bf16* __restrict__ Z)
{
  const int bid = blockIdx.x;
  const int mt = bid / 20, kt = bid % 20;
  __bf16* zdst = Z + ((size_t)bid << 12);      // 4096 elems per (mt,kt)

#pragma unroll
  for (int c = 0; c < 2; ++c) {
    const int o = c * 2048 + threadIdx.x * 8;  // linear offset in 4096-elem tile
    const int r = o >> 5;                      // row 0..127
    const int cc = (o >> 3) & 3;               // stored 16B chunk
    const int k = kt * 32 + ((cc ^ (r & 3)) << 3);  // original k (inverse swz32)
    const int grow = mt * 128 + r;             // global M-row = ((b*256+t)*64+u)
    const __bf16* ep = E + (size_t)(grow >> 6) * 640 + k;
    const __bf16* pp = P + (size_t)(((grow >> 14) << 6) | (grow & 63)) * 640 + k;
    bf16x8 e8 = *(const bf16x8*)ep;
    bf16x8 p8 = *(const bf16x8*)pp;
    bf16x8 z;
#pragma unroll
    for (int j = 0; j < 8; ++j)
      z[j] = (__bf16)fast_tanh((float)e8[j] + (float)p8[j]);
    *(bf16x8*)&zdst[o] = z;
  }
}

// ---------------------------------------------------------------------------
// main (Z-path): pure bf16 GEMM, TLP-first 2-phase loop.
// Tile 128(M) x 256(N), BK=32, 20 K-tiles, 512 thr = 8 waves (2M x 4N),
// wave-tile 64x64 (acc 64 VGPR).  LDS dbuf 48 KB -> 2 blocks/CU (m114
// cross-block overlap covers barriers/prologue/epilogue).  Per K-tile:
// stage(k+1) [3 gload_lds], 8 ds_read_b128, 16 MFMA (setprio), vmcnt(0)
// draining loads issued one full phase earlier (lag-1 counted wait), barrier.
// Grid 2048 = 512 mt x 4 nt, XCD-swizzled (2048 % 8 == 0); the 4 nt-blocks
// of an mt are consecutive -> same XCD L2 for Z re-reads.
// ---------------------------------------------------------------------------
__global__ __launch_bounds__(512, 4) void joiner_2ph(
    const __bf16* __restrict__ Z, const __bf16* __restrict__ Wb,
    const float* __restrict__ outb, float* __restrict__ out)
{
  __shared__ __align__(16) __bf16 As[2][4096];   // 16 KB
  __shared__ __align__(16) __bf16 Bs[2][8192];   // 32 KB
  const int wg = blockIdx.x;
  const int bid = (wg & 7) * 256 + (wg >> 3);    // XCD-contiguous chunks
  const int mt = bid >> 2, nt = bid & 3;
  const int tid = threadIdx.x;
  const int lane = tid & 63, wv = tid >> 6;
  const int wm = wv >> 2, wn = wv & 3;           // 2 x 4 wave grid
  const int q = lane & 15;
  const int chunk = (((lane >> 4) ^ (q & 3)) << 3);

  const __bf16* zsrc = Z  + (size_t)mt * 81920;  // 20 * 4096
  const __bf16* wsrc = Wb + (size_t)nt * 163840; // 20 * 2 * 4096

  const int abase = (wm * 64 + q) * 32 + chunk;  // + mi*512
  const int bbase = (wn * 64 + q) * 32 + chunk;  // + ni*512  (rows 0..255 contiguous)

  f32x4 acc[4][4] = {};

  auto stage = [&](int k) {
    const int d = k & 1;
    const int wo = wv * 512;
    gload_lds16(zsrc + k * 4096 + wo + lane * 8, &As[d][wo]);
    gload_lds16(wsrc + k * 8192 + wo + lane * 8, &Bs[d][wo]);
    gload_lds16(wsrc + k * 8192 + 4096 + wo + lane * 8, &Bs[d][4096 + wo]);
  };

  // prologue
  stage(0);
  asm volatile("s_waitcnt vmcnt(0)" ::: "memory");
  __builtin_amdgcn_s_barrier();

#pragma unroll 2
  for (int k = 0; k < 20; ++k) {
    const int d = k & 1;
    if (k < 19) stage(k + 1);                 // lag-1 prefetch into buf d^1
    bf16x8 af[4], bfr[4];
#pragma unroll
    for (int mi = 0; mi < 4; ++mi)
      af[mi] = *(const bf16x8*)&As[d][abase + mi * 512];
#pragma unroll
    for (int ni = 0; ni < 4; ++ni)
      bfr[ni] = *(const bf16x8*)&Bs[d][bbase + ni * 512];
    __builtin_amdgcn_s_setprio(1);
#pragma unroll
    for (int mi = 0; mi < 4; ++mi)
#pragma unroll
      for (int ni = 0; ni < 4; ++ni)
        acc[mi][ni] = __builtin_amdgcn_mfma_f32_16x16x32_bf16(af[mi], bfr[ni], acc[mi][ni], 0, 0, 0);
    __builtin_amdgcn_s_setprio(0);
    if (k < 19) {
      asm volatile("s_waitcnt vmcnt(0)" ::: "memory");  // drains k+1's loads (issued 1 phase ago)
      __builtin_amdgcn_s_barrier();
    }
  }

  // epilogue: bias + store (64B-coalesced segments)
  const int rowbase = (mt << 7) + wm * 64;
  const int colbase = (nt << 8) + wn * 64;
#pragma unroll
  for (int ni = 0; ni < 4; ++ni) {
    const int col = colbase + ni * 16 + q;
    const float bb = outb[col];
#pragma unroll
    for (int mi = 0; mi < 4; ++mi) {
      const int row = rowbase + mi * 16 + (lane >> 4) * 4;
#pragma unroll
      for (int rg = 0; rg < 4; ++rg)
        out[(size_t)(row + rg) * 1024 + col] = acc[mi][ni][rg] + bb;
    }
  }
}

// ---------------------------------------------------------------------------
// Fallback (small ws): R5 fused kernel, Wb in [8][10][128x64 swz64] layout.
// ---------------------------------------------------------------------------
__global__ __launch_bounds__(512, 4) void joiner_fused(
    const __bf16* __restrict__ E, const __bf16* __restrict__ P,
    const __bf16* __restrict__ Wb, const float* __restrict__ outb,
    float* __restrict__ out)
{
  __shared__ __align__(16) __bf16 As[8192];
  __shared__ __align__(16) __bf16 Bs[2][16384];
  const int tid = threadIdx.x;
  const int nt = blockIdx.x & 3;
  const int mt = blockIdx.x >> 2;
  const int row0 = mt << 7;
  const int b  = row0 >> 14;
  const int t0 = (row0 >> 6) & 255;
  const int ar = tid & 127, h = tid >> 7;
  const int lane = tid & 63, wv = tid >> 6;
  const int wm = wv >> 2, wn = wv & 3;

  const __bf16* ep = E + (size_t)((b << 8) + t0 + (ar >> 6)) * 640 + h * 16;
  const __bf16* pp = P + (size_t)((b << 6) + (ar & 63)) * 640 + h * 16;

  f32x4 acc[4][4] = {};
  bf16x8 eA[2], pA[2];

  auto stageB2 = [&](int kt, __bf16* dst) {
#pragma unroll
    for (int c = 0; c < 4; ++c) {
      const int blk = nt * 2 + (c >> 1);
      const int inoff = (c & 1) * 4096 + wv * 512;
      gload_lds16(Wb + ((size_t)(blk * 10 + kt) << 13) + inoff + lane * 8,
                  dst + (c >> 1) * 8192 + inoff);
    }
  };
  auto loadEP = [&](int k0) {
#pragma unroll
    for (int c = 0; c < 2; ++c) {
      eA[c] = *(const bf16x8*)(ep + k0 + c * 8);
      pA[c] = *(const bf16x8*)(pp + k0 + c * 8);
    }
  };
  auto writeA = [&]() {
#pragma unroll
    for (int c = 0; c < 2; ++c) {
      bf16x8 z;
#pragma unroll
      for (int j = 0; j < 8; ++j)
        z[j] = (__bf16)fast_tanh((float)eA[c][j] + (float)pA[c][j]);
      *(bf16x8*)&As[swz64(ar, h * 16 + c * 8)] = z;
    }
  };
  auto compute = [&](const __bf16* Bsc) {
#pragma unroll
    for (int kk = 0; kk < 2; ++kk) {
      bf16x8 af[4], bfr[4];
#pragma unroll
      for (int i = 0; i < 4; ++i) {
        af[i]  = *(const bf16x8*)&As[swz64(wm * 64 + i * 16 + (lane & 15), kk * 32 + (lane >> 4) * 8)];
        bfr[i] = *(const bf16x8*)&Bsc[swz64(wn * 64 + i * 16 + (lane & 15), kk * 32 + (lane >> 4) * 8)];
      }
      asm volatile("s_waitcnt lgkmcnt(0)" ::: "memory");
      __builtin_amdgcn_sched_barrier(0);
      __builtin_amdgcn_s_setprio(1);
#pragma unroll
      for (int mi = 0; mi < 4; ++mi)
#pragma unroll
        for (int ni = 0; ni < 4; ++ni)
          acc[mi][ni] = __builtin_amdgcn_mfma_f32_16x16x32_bf16(af[mi], bfr[ni], acc[mi][ni], 0, 0, 0);
      __builtin_amdgcn_s_setprio(0);
    }
  };

  stageB2(0, Bs[0]);
  loadEP(0);
  writeA();
  asm volatile("s_waitcnt vmcnt(0) lgkmcnt(0)" ::: "memory");
  __builtin_amdgcn_s_barrier();

  for (int kt = 0; kt < 9; ++kt) {
    const int cur = kt & 1;
    stageB2(kt + 1, Bs[cur ^ 1]);
    loadEP((kt + 1) << 6);
    compute(Bs[cur]);
    __builtin_amdgcn_s_barrier();
    __builtin_amdgcn_sched_barrier(0);
    writeA();
    asm volatile("s_waitcnt lgkmcnt(0)" ::: "memory");
    __builtin_amdgcn_s_barrier();
  }
  compute(Bs[1]);

  const int rowbase = row0 + wm * 64;
  const int colbase = (nt << 8) + wn * 64;
#pragma unroll
  for (int ni = 0; ni < 4; ++ni) {
    const int col = colbase + ni * 16 + (lane & 15);
    const float bb = outb[col];
#pragma unroll
    for (int mi = 0; mi < 4; ++mi) {
      const int row = rowbase + mi * 16 + (lane >> 4) * 4;
#pragma unroll
      for (int rg = 0; rg < 4; ++rg)
        out[(size_t)(row + rg) * 1024 + col] = acc[mi][ni][rg] + bb;
    }
  }
}

extern "C" void kernel_launch(void* const* d_in, const int* in_sizes, int n_in,
                              void* d_out, int out_size, void* d_ws, size_t ws_size,
                              hipStream_t stream) {
  const float* enc    = (const float*)d_in[0];
  const float* pred   = (const float*)d_in[1];
  const float* enc_w  = (const float*)d_in[2];
  const float* enc_b  = (const float*)d_in[3];
  const float* pred_w = (const float*)d_in[4];
  const float* pred_b = (const float*)d_in[5];
  const float* out_w  = (const float*)d_in[6];
  const float* out_b  = (const float*)d_in[7];
  float* out = (float*)d_out;

  char* ws = (char*)d_ws;
  __bf16* E  = (__bf16*)(ws);                 // 1024*640 bf16
  __bf16* P  = (__bf16*)(ws + 1310720);       //  256*640 bf16
  __bf16* Wb = (__bf16*)(ws + 1638400);       // pre-swizzled out_w tiles
  __bf16* Z  = (__bf16*)(ws + 2949120);       // 512*20*4096 bf16, pre-swizzled

  const int zpath = (ws_size >= (size_t)86835200) ? 1 : 0;

  prep_kernel<<<dim3(370), dim3(256), 0, stream>>>(
      enc, enc_w, enc_b, pred, pred_w, pred_b, out_w, E, P, Wb, zpath);

  if (zpath) {
    zprod_kernel<<<dim3(10240), dim3(256), 0, stream>>>(E, P, Z);
    joiner_2ph<<<dim3(2048), dim3(512), 0, stream>>>(Z, Wb, out_b, out);
  } else {
    joiner_fused<<<dim3(2048), dim3(512), 0, stream>>>(E, P, Wb, out_b, out);
  }
}